// Round 9
// baseline (464.691 us; speedup 1.0000x reference)
//
#include <hip/hip_runtime.h>
#include <cstddef>
#include <cstdint>

#define GAMMA_F 0.99f
#define OMG_F   0.01f      // 1 - gamma
#define EPS_F   1e-5f
#define KN 8192
#define DD 256
#define NN 32768           // B*T

// output layout (float offsets)
#define OFF_ZQ     0
#define OFF_COMMIT 8388608
#define OFF_IDX    8388609
#define OFF_EMB    8421377
#define OFF_MT     10518529
#define OFF_NT     12615681

typedef _Float16 half8 __attribute__((ext_vector_type(8)));
typedef _Float16 half4 __attribute__((ext_vector_type(4)));
typedef float    f32x4 __attribute__((ext_vector_type(4)));
typedef unsigned long long u64;

// ---------------------------------------------------------------------------
// async 16B global->LDS (DMA: lane i -> lds_base + i*16; base wave-uniform,
// global address must be 16B aligned)
__device__ __forceinline__ void gload16(const void* g, void* l) {
    __builtin_amdgcn_global_load_lds(
        (const __attribute__((address_space(1))) unsigned int*)g,
        (__attribute__((address_space(3))) unsigned int*)l, 16, 0, 0);
}

// sortable pack for exact fp32 rescoring (dist may be negative)
__device__ __forceinline__ u64 packdi(float dist, int n) {
    unsigned u = __float_as_uint(dist);
    u ^= (unsigned)((int)u >> 31) | 0x80000000u;
    return ((u64)u << 32) | (unsigned)n;
}

// ---------------------------------------------------------------------------
// ze -> f16(-2*z) (exact pow2 scale; bakes the -2 of dist = wsq - 2 z.w into
// the MFMA so the accumulator IS the biased distance)
__global__ __launch_bounds__(256) void conv_hi_kernel(
    const float* __restrict__ x, _Float16* __restrict__ hi) {
    const size_t i0 = ((size_t)blockIdx.x * 256 + threadIdx.x) * 4;
    const float4 v = *(const float4*)(x + i0);
    half4 h;
    h[0] = (_Float16)(-2.0f * v.x); h[1] = (_Float16)(-2.0f * v.y);
    h[2] = (_Float16)(-2.0f * v.z); h[3] = (_Float16)(-2.0f * v.w);
    *(half4*)(hi + i0) = h;
}

// ---------------------------------------------------------------------------
// fused: W row -> f16 copy + (||w||^2 + 4096). One wave per code row.
__global__ __launch_bounds__(64) void convw_wsq_kernel(
    const float* __restrict__ W, _Float16* __restrict__ wh,
    float* __restrict__ wsq) {
    const int k = blockIdx.x;
    const int lane = threadIdx.x;
    const float4 v = *(const float4*)(W + (size_t)k * DD + lane * 4);
    half4 h;
    h[0] = (_Float16)v.x; h[1] = (_Float16)v.y;
    h[2] = (_Float16)v.z; h[3] = (_Float16)v.w;
    *(half4*)(wh + (size_t)k * DD + lane * 4) = h;
    float s = v.x * v.x + v.y * v.y + v.z * v.z + v.w * v.w;
#pragma unroll
    for (int off = 32; off > 0; off >>= 1) s += __shfl_down(s, off, 64);
    if (lane == 0) wsq[k] = s + 4096.0f;
}

// ---------------------------------------------------------------------------
// Screening GEMM, f16, K=256. Block = 128 points x 128 codes, 4 waves (2x2).
// A=codes, B=points(-2z); acc init = wsq+4096 => acc = biased dist directly.
// Top-2 per (point, 128-code tile) on u32-packed (distbits&~127 | code7):
// per dist: and_or + min + max/min (no fma, no separate bias).
__global__ __launch_bounds__(256, 4) void screen_kernel(
    const _Float16* __restrict__ zh, const _Float16* __restrict__ wh,
    const float* __restrict__ wsq, u64* __restrict__ tmin2) {
    __shared__ __align__(16) _Float16 As[128 * 64];   // points tile, 16 KB
    __shared__ __align__(16) _Float16 Bs[128 * 64];   // codes tile, 16 KB
    __shared__ __align__(16) u64 top2[128][2];        // [point][code-half]

    const int tid  = threadIdx.x;
    const int wave = tid >> 6;
    const int lane = tid & 63;
    const int quad = lane >> 4;
    const int col  = lane & 15;
    const int ph = wave & 1;        // point half of the block tile
    const int ch = wave >> 1;       // code half
    const int pw = ph * 64;
    const int cw = ch * 64;

    const int bm = blockIdx.x >> 6;     // point-block
    const int bn = blockIdx.x & 63;     // code-block
    const int m0 = bm * 128;
    const int n0 = bn * 128;

    f32x4 acc[4][4];                // [ci (codes)][pj (points)]
#pragma unroll
    for (int ci = 0; ci < 4; ci++) {
        const float4 t = *(const float4*)(wsq + n0 + cw + ci * 16 + quad * 4);
        const f32x4 iv = {t.x, t.y, t.z, t.w};   // wsq + 4096 (pre-offset)
#pragma unroll
        for (int pj = 0; pj < 4; pj++) acc[ci][pj] = iv;
    }

    for (int c = 0; c < 4; ++c) {            // K = 256, 4 chunks of 64
        const int d0 = c * 64;
        __syncthreads();
#pragma unroll
        for (int i = 0; i < 4; ++i) {
            const int clin = (wave * 4 + i) * 64 + lane;   // 0..1023
            const int mrow = clin >> 3;
            const int p = clin & 7;
            const int q = p ^ (mrow & 7);                  // swizzled k-chunk
            gload16(zh + (size_t)(m0 + mrow) * DD + d0 + q * 8,
                    As + (wave * 4 + i) * 512);
            gload16(wh + (size_t)(n0 + mrow) * DD + d0 + q * 8,
                    Bs + (wave * 4 + i) * 512);
        }
        __syncthreads();

#pragma unroll
        for (int kk = 0; kk < 2; ++kk) {
            half8 a[4], b[4];
#pragma unroll
            for (int t = 0; t < 4; ++t) {
                const int cr = cw + t * 16 + col;   // code row
                const int pr = pw + t * 16 + col;   // point row
                const int cc = kk * 4 + quad;
                a[t] = *(const half8*)(Bs + cr * 64 + (cc ^ (cr & 7)) * 8);
                b[t] = *(const half8*)(As + pr * 64 + (cc ^ (pr & 7)) * 8);
            }
#pragma unroll
            for (int ci = 0; ci < 4; ++ci)
#pragma unroll
                for (int pj = 0; pj < 4; ++pj)
                    acc[ci][pj] = __builtin_amdgcn_mfma_f32_16x16x32_f16(
                        a[ci], b[pj], acc[ci][pj], 0, 0, 0);
        }
    }

    const unsigned base7 = (unsigned)(cw + quad * 4);

#pragma unroll
    for (int pj = 0; pj < 4; ++pj) {
        unsigned t0 = 0xFFFFFFFFu, t1 = 0xFFFFFFFFu;
#pragma unroll
        for (int ci = 0; ci < 4; ++ci)
#pragma unroll
            for (int v = 0; v < 4; ++v) {
                // acc is the biased distance (positive -> bits monotone)
                const unsigned x = (__float_as_uint(acc[ci][pj][v]) & ~127u) |
                                   (base7 + ci * 16 + v);
                const unsigned mx = t0 > x ? t0 : x;
                t0 = t0 < x ? t0 : x;
                t1 = t1 < mx ? t1 : mx;
            }
        // merge sorted pairs across the 4 quads (same point col)
#pragma unroll
        for (int mk = 16; mk < 64; mk <<= 1) {
            const unsigned o0 = __shfl_xor(t0, mk, 64);
            const unsigned o1 = __shfl_xor(t1, mk, 64);
            const unsigned lo = t0 < o0 ? t0 : o0;
            const unsigned hi = t0 < o0 ? o0 : t0;
            const unsigned mn = t1 < o1 ? t1 : o1;
            t0 = lo;
            t1 = hi < mn ? hi : mn;
        }
        if (quad == 0)
            top2[pw + pj * 16 + col][ch] = ((u64)t1 << 32) | t0;
    }
    __syncthreads();
    if (tid < 128) {
        const u64 e0 = top2[tid][0], e1 = top2[tid][1];
        const unsigned a0 = (unsigned)e0, a1 = (unsigned)(e0 >> 32);
        const unsigned b0 = (unsigned)e1, b1 = (unsigned)(e1 >> 32);
        const unsigned t0 = a0 < b0 ? a0 : b0;
        const unsigned hi = a0 < b0 ? b0 : a0;
        const unsigned mn = a1 < b1 ? a1 : b1;
        const unsigned t1 = hi < mn ? hi : mn;
        const unsigned c1 = n0 + (t0 & 127u);
        const unsigned c2 = n0 + (t1 & 127u);
        const u64 ent = (u64)(t0 & ~127u) | ((u64)c1 << 32) | ((u64)c2 << 48);
        // transposed layout [tile][point] -> fully coalesced 1KB block write
        tmin2[(size_t)bn * NN + m0 + tid] = ent;
    }
}

// ---------------------------------------------------------------------------
// Thread-per-point two-pass compaction (coalesced 256-wide tmin2 reads; pass 2
// hits L2 — per-block working set is 128 KB). Fused: mt_acc = gamma*mt_in,
// nt_acc = gamma*Nt_in, commit = 0, Ssum = sum(Nt_in). Grid = NN/256 = 128.
__global__ __launch_bounds__(256) void compact_kernel(
    const u64* __restrict__ tmin2, unsigned* __restrict__ cnt,
    unsigned* __restrict__ slots, const float* __restrict__ mt_in,
    float* __restrict__ mt_acc, const float* __restrict__ Nt_in,
    float* __restrict__ nt_acc, float* __restrict__ commit_zero,
    float* __restrict__ Ssum) {
    const int tid = threadIdx.x;
    const int gid = blockIdx.x * 256 + tid;   // point id 0..NN-1

    // gamma-init of the mt accumulator: 16 float4 per thread covers KN*DD
    for (int r = 0; r < 16; ++r) {
        const size_t i4 = ((size_t)r * NN + gid) * 4;
        const float4 m = *(const float4*)(mt_in + i4);
        float4 o;
        o.x = GAMMA_F * m.x; o.y = GAMMA_F * m.y;
        o.z = GAMMA_F * m.z; o.w = GAMMA_F * m.w;
        *(float4*)(mt_acc + i4) = o;
    }
    if (gid < KN) nt_acc[gid] = GAMMA_F * Nt_in[gid];
    if (gid == 0) *commit_zero = 0.f;
    if (blockIdx.x == 0 && Ssum != nullptr) {
        __shared__ float red[256];
        float s = 0.f;
        for (int i = tid; i < KN; i += 256) s += Nt_in[i];
        red[tid] = s;
        __syncthreads();
        for (int off = 128; off > 0; off >>= 1) {
            if (tid < off) red[tid] += red[tid + off];
            __syncthreads();
        }
        if (tid == 0) *Ssum = red[0];
    }

    // pass 1: min screened dist over the point's 64 tile records
    float mn = 3.4e38f;
    for (int j = 0; j < 64; ++j) {
        const u64 e = tmin2[(size_t)j * NN + gid];
        mn = fminf(mn, __uint_as_float((unsigned)e));
    }
    // pass 2: collect candidates within the safety window
    const float lim = mn + 1.0f;   // >=25-sigma of f16 screen error + quant
    int rank = 0;
    for (int j = 0; j < 64; ++j) {
        const u64 e = tmin2[(size_t)j * NN + gid];
        if (__uint_as_float((unsigned)e) <= lim && rank < 32) {
            slots[(size_t)gid * 32 + rank]     = (unsigned)(e >> 32) & 0xffffu;
            slots[(size_t)gid * 32 + rank + 1] = (unsigned)(e >> 48);
            rank += 2;
        }
    }
    cnt[gid] = rank;
}

// ---------------------------------------------------------------------------
// Fused: exact fp32 rescore of candidates -> winning index; then gather zq,
// write zq_st, commit-loss reduce, one-hot scatter onto gamma-initialized
// accumulators. One wave per point.
__global__ __launch_bounds__(256) void rescore_gather_kernel(
    const float* __restrict__ ze, const float* __restrict__ W,
    const unsigned* __restrict__ cnt, const unsigned* __restrict__ slots,
    float* __restrict__ idxf, float* __restrict__ zq_out,
    float* __restrict__ commit_acc, float* __restrict__ mt_acc,
    float* __restrict__ nt_acc) {
    const int tid = threadIdx.x;
    const int lane = tid & 63;
    const int n = blockIdx.x * 4 + (tid >> 6);
    const float4 z = *(const float4*)(ze + (size_t)n * DD + lane * 4);
    const unsigned m = cnt[n];
    u64 best = ~0ull;
    for (unsigned j = 0; j < m; ++j) {
        const unsigned c = slots[(size_t)n * 32 + j];
        const float4 w = *(const float4*)(W + (size_t)c * DD + lane * 4);
        float dot = z.x * w.x + z.y * w.y + z.z * w.z + z.w * w.w;
        float wq  = w.x * w.x + w.y * w.y + w.z * w.z + w.w * w.w;
#pragma unroll
        for (int off = 32; off > 0; off >>= 1) {
            dot += __shfl_xor(dot, off, 64);
            wq  += __shfl_xor(wq, off, 64);
        }
        const float dist = fmaf(-2.0f, dot, wq);
        const u64 pk = packdi(dist, (int)c);
        best = best < pk ? best : pk;
    }
    const int idx = (int)(unsigned)(best & 0xFFFFFFFFull);  // wave-uniform
    if (lane == 0) idxf[n] = (float)idx;

    const float4 w = *(const float4*)(W + (size_t)idx * DD + lane * 4);
    float4 d, o;
    d.x = w.x - z.x; d.y = w.y - z.y; d.z = w.z - z.z; d.w = w.w - z.w;
    o.x = z.x + d.x; o.y = z.y + d.y; o.z = z.z + d.z; o.w = z.w + d.w;
    *(float4*)(zq_out + (size_t)n * DD + lane * 4) = o;

    float* mp = mt_acc + (size_t)idx * DD + lane * 4;
    atomicAdd(mp + 0, OMG_F * z.x);
    atomicAdd(mp + 1, OMG_F * z.y);
    atomicAdd(mp + 2, OMG_F * z.z);
    atomicAdd(mp + 3, OMG_F * z.w);
    if (lane == 0) atomicAdd(nt_acc + idx, OMG_F);

    float c = d.x * d.x + d.y * d.y + d.z * d.z + d.w * d.w;
#pragma unroll
    for (int off = 32; off > 0; off >>= 1) c += __shfl_down(c, off, 64);

    __shared__ float wsum[4];
    if (lane == 0) wsum[tid >> 6] = c;
    __syncthreads();
    if (tid == 0) {
        const float part = wsum[0] + wsum[1] + wsum[2] + wsum[3];
        atomicAdd(commit_acc, part * (1.0f / 8388608.0f));
    }
}

// ---------------------------------------------------------------------------
// mt region already holds mt_new (gamma-init + atomics). Compute
// n = gamma*Sum(Nt) + 0.01*NN (Sum(nt) == NN exactly), Nn, emb = mt_new/Nn.
__global__ __launch_bounds__(256) void final_kernel(
    const float* __restrict__ nt_new, const float* __restrict__ Ssum,
    const float* __restrict__ mt_new, float* __restrict__ emb_out) {
    float n;
    if (Ssum != nullptr) {
        n = GAMMA_F * (*Ssum) + OMG_F * (float)NN;
    } else {
        __shared__ float red[256];
        float s = 0.f;
        for (int i = threadIdx.x; i < KN; i += 256) s += nt_new[i];
        red[threadIdx.x] = s;
        __syncthreads();
        for (int off = 128; off > 0; off >>= 1) {
            if (threadIdx.x < off) red[threadIdx.x] += red[threadIdx.x + off];
            __syncthreads();
        }
        n = red[0];
    }

    const size_t i0 = ((size_t)blockIdx.x * 256 + threadIdx.x) * 4;
    const int k = (int)(i0 >> 8);
    const float4 m = *(const float4*)(mt_new + i0);
    const float Nn = (nt_new[k] + EPS_F) * n / (n + (float)KN * EPS_F);
    float4 e;
    e.x = m.x / Nn; e.y = m.y / Nn; e.z = m.z / Nn; e.w = m.w / Nn;
    *(float4*)(emb_out + i0) = e;
}

// ---------------------------------------------------------------------------
extern "C" void kernel_launch(void* const* d_in, const int* in_sizes, int n_in,
                              void* d_out, int out_size, void* d_ws, size_t ws_size,
                              hipStream_t stream) {
    const float* ze = (const float*)d_in[0];
    const float* W  = (const float*)d_in[1];
    const float* mt = (const float*)d_in[2];
    const float* Nt = (const float*)d_in[3];

    float* out    = (float*)d_out;
    float* zq_out = out + OFF_ZQ;
    float* commit = out + OFF_COMMIT;
    float* idxf   = out + OFF_IDX;
    float* emb    = out + OFF_EMB;
    float* mtn    = out + OFF_MT;
    float* ntn    = out + OFF_NT;

    // ---- scratch aliases (aligned; all consumed before real outputs written)
    _Float16* zh = (_Float16*)zq_out;                  // NN*DD halfs (16.7 MB)
    u64* tmin2 =                                       // [64 tiles][NN points]
        (u64*)(zq_out + (size_t)NN * DD / 2);
    _Float16* wh = (_Float16*)(mtn + 3);               // 16B-aligned, in mt rgn
    float* wsqbuf = idxf + 3;                          // 16B-aligned, idx rgn
    unsigned* cnt   = (unsigned*)emb;                  // NN u32
    unsigned* slots = (unsigned*)emb + NN;             // NN*32 u32 (4.2 MB)
    float* Ssum = (ws_size >= sizeof(float)) ? (float*)d_ws : nullptr;

    // 1) conversions: z -> f16(-2z); W -> f16 + (||w||^2 + 4096)
    conv_hi_kernel<<<(NN * DD / 4) / 256, 256, 0, stream>>>(ze, zh);
    convw_wsq_kernel<<<KN, 64, 0, stream>>>(W, wh, wsqbuf);

    // 2) f16 screening GEMM -> per-(point,tile) top-2 records
    screen_kernel<<<(NN / 128) * (KN / 128), 256, 0, stream>>>(
        zh, wh, wsqbuf, tmin2);

    // 3) compaction (coalesced) + gamma-init of mt/nt + commit=0 + Ssum
    compact_kernel<<<NN / 256, 256, 0, stream>>>(tmin2, cnt, slots,
                                                 mt, mtn, Nt, ntn,
                                                 commit, Ssum);

    // 4) exact fp32 rescore + gather + commit + one-hot scatter (fused)
    rescore_gather_kernel<<<NN / 4, 256, 0, stream>>>(
        ze, W, cnt, slots, idxf, zq_out, commit, mtn, ntn);

    // 5) n, Nn, embedW_new (mt/nt already final in place)
    final_kernel<<<(KN * DD / 4) / 256, 256, 0, stream>>>(ntn, Ssum, mtn, emb);
}